// Round 1
// baseline (1503.802 us; speedup 1.0000x reference)
//
#include <hip/hip_runtime.h>
#include <hip/hip_bf16.h>

// GraphConv x2:  h = sigmoid(mean_agg(x*w) @ Wrel1^T + b1 + x @ Wroot1^T)
//                out = mean_agg(h*w) @ Wrel2^T + b2 + h @ Wroot2^T
// Trick: layer-2 aggregation commutes with the linear layer, so pre-transform
// hr = h @ Wrel2^T (64->32) and scatter the 32-wide hr instead of 64-wide h.

#define NF 64

// ---------------- dtype detection (int64 vs int32 edge_index) ---------------
__global__ void detect_i64(const unsigned* __restrict__ raw, int* __restrict__ flag) {
    __shared__ unsigned red[256];
    unsigned v = 0;
    for (int i = threadIdx.x; i < 4096; i += 256) v |= raw[2 * i + 1];
    red[threadIdx.x] = v;
    __syncthreads();
    for (int s = 128; s > 0; s >>= 1) {
        if (threadIdx.x < s) red[threadIdx.x] |= red[threadIdx.x + s];
        __syncthreads();
    }
    if (threadIdx.x == 0) *flag = (red[0] == 0) ? 1 : 0;  // all-high-dwords-zero => int64
}

__global__ void convert_idx(const void* __restrict__ raw, const int* __restrict__ flag,
                            int* __restrict__ src, int* __restrict__ dst, int E) {
    int e = blockIdx.x * blockDim.x + threadIdx.x;
    if (e >= E) return;
    if (*flag) {
        const long long* p = (const long long*)raw;
        src[e] = (int)p[e];
        dst[e] = (int)p[E + e];
    } else {
        const int* p = (const int*)raw;
        src[e] = p[e];
        dst[e] = p[E + e];
    }
}

// ---------------- scatter layer 1: agg1 += w * x[src], cnt += 1 -------------
__global__ __launch_bounds__(256) void scatter64(
    const float* __restrict__ x, const int* __restrict__ src, const int* __restrict__ dst,
    const float* __restrict__ ea, float* __restrict__ agg, float* __restrict__ cnt, int E)
{
    int tid = blockIdx.x * blockDim.x + threadIdx.x;
    int e = tid >> 4, c = tid & 15;          // 16 threads/edge, float4 each
    if (e >= E) return;
    int s = src[e], d = dst[e];
    float w = ea[e];
    float4 v = *(const float4*)(x + (size_t)s * 64 + c * 4);
    float* a = agg + (size_t)d * 64 + c * 4;
    atomicAdd(a + 0, v.x * w);
    atomicAdd(a + 1, v.y * w);
    atomicAdd(a + 2, v.z * w);
    atomicAdd(a + 3, v.w * w);
    if (c == 0) atomicAdd(cnt + d, 1.0f);
}

// ---------------- scatter layer 2: agg2 += w * hr[src] (32 wide) ------------
__global__ __launch_bounds__(256) void scatter32(
    const float* __restrict__ hr, const int* __restrict__ src, const int* __restrict__ dst,
    const float* __restrict__ ea, float* __restrict__ agg, int E)
{
    int tid = blockIdx.x * blockDim.x + threadIdx.x;
    int e = tid >> 3, c = tid & 7;           // 8 threads/edge, float4 each
    if (e >= E) return;
    int s = src[e], d = dst[e];
    float w = ea[e];
    float4 v = *(const float4*)(hr + (size_t)s * 32 + c * 4);
    float* a = agg + (size_t)d * 32 + c * 4;
    atomicAdd(a + 0, v.x * w);
    atomicAdd(a + 1, v.y * w);
    atomicAdd(a + 2, v.z * w);
    atomicAdd(a + 3, v.w * w);
}

// ---- layer-1 node transform: h = sigmoid((agg/cnt)@Wrel1^T + b1 + x@Wroot1^T)
// ---- fused: hr = h @ Wrel2^T
__global__ __launch_bounds__(256) void node1(
    const float* __restrict__ x, const float* __restrict__ agg,
    const float* __restrict__ cnt,
    const float* __restrict__ Wrel1, const float* __restrict__ brel1,
    const float* __restrict__ Wroot1, const float* __restrict__ Wrel2,
    float* __restrict__ h, float* __restrict__ hr, int N)
{
    __shared__ float wrel[64 * 65];   // transposed [k][f], pad 65 -> 2-way max
    __shared__ float wroot[64 * 65];
    __shared__ float wrel2[64 * 33];  // transposed [f][j], j<32
    __shared__ float xs[4][64], as_[4][64], hs[4][64];
    int t = threadIdx.x;
    for (int i = t; i < 4096; i += 256) {
        int f = i >> 6, k = i & 63;
        wrel[k * 65 + f] = Wrel1[i];
        wroot[k * 65 + f] = Wroot1[i];
    }
    for (int i = t; i < 2048; i += 256) {
        int j = i >> 6, f = i & 63;   // Wrel2 is [32][64] row-major
        wrel2[f * 33 + j] = Wrel2[i];
    }
    int lane = t & 63, wv = t >> 6;
    int n = blockIdx.x * 4 + wv;
    float xv = 0.f, av = 0.f;
    if (n < N) {
        xv = x[(size_t)n * 64 + lane];
        av = agg[(size_t)n * 64 + lane] * (1.0f / fmaxf(cnt[n], 1.0f));
    }
    xs[wv][lane] = xv;
    as_[wv][lane] = av;
    __syncthreads();

    float accr = brel1[lane], acco = 0.f;
#pragma unroll
    for (int k = 0; k < 64; ++k) {
        accr = fmaf(as_[wv][k], wrel[k * 65 + lane], accr);
        acco = fmaf(xs[wv][k], wroot[k * 65 + lane], acco);
    }
    float hv = 1.0f / (1.0f + __expf(-(accr + acco)));
    if (n < N) h[(size_t)n * 64 + lane] = hv;
    hs[wv][lane] = hv;
    __syncthreads();

    // hr[j] = sum_f h[f]*Wrel2[j][f]; split K across lane halves
    int j = lane & 31, half = lane >> 5;
    float acc2 = 0.f;
#pragma unroll
    for (int k2 = 0; k2 < 32; ++k2) {
        int f = half * 32 + k2;
        acc2 = fmaf(hs[wv][f], wrel2[f * 33 + j], acc2);
    }
    acc2 += __shfl_xor(acc2, 32);
    if (half == 0 && n < N) hr[(size_t)n * 32 + j] = acc2;
}

// ---- layer-2 epilogue: out = agg2/cnt + b2 + h @ Wroot2^T -------------------
__global__ __launch_bounds__(256) void node2(
    const float* __restrict__ h, const float* __restrict__ agg2,
    const float* __restrict__ cnt, const float* __restrict__ Wroot2,
    const float* __restrict__ brel2, float* __restrict__ out, int N)
{
    __shared__ float wroot[64 * 33];
    __shared__ float hs[4][64];
    int t = threadIdx.x;
    for (int i = t; i < 2048; i += 256) {
        int j = i >> 6, f = i & 63;   // Wroot2 is [32][64] row-major
        wroot[f * 33 + j] = Wroot2[i];
    }
    int lane = t & 63, wv = t >> 6;
    int n = blockIdx.x * 4 + wv;
    float hv = 0.f;
    if (n < N) hv = h[(size_t)n * 64 + lane];
    hs[wv][lane] = hv;
    __syncthreads();

    int j = lane & 31, half = lane >> 5;
    float acc = 0.f;
#pragma unroll
    for (int k2 = 0; k2 < 32; ++k2) {
        int f = half * 32 + k2;
        acc = fmaf(hs[wv][f], wroot[f * 33 + j], acc);
    }
    acc += __shfl_xor(acc, 32);
    if (half == 0 && n < N) {
        float inv = 1.0f / fmaxf(cnt[n], 1.0f);
        out[(size_t)n * 32 + j] = acc + agg2[(size_t)n * 32 + j] * inv + brel2[j];
    }
}

extern "C" void kernel_launch(void* const* d_in, const int* in_sizes, int n_in,
                              void* d_out, int out_size, void* d_ws, size_t ws_size,
                              hipStream_t stream) {
    const float* x      = (const float*)d_in[0];
    const void*  ei_raw = d_in[1];
    const float* ea     = (const float*)d_in[2];
    const float* Wrel1  = (const float*)d_in[3];
    const float* brel1  = (const float*)d_in[4];
    const float* Wroot1 = (const float*)d_in[5];
    const float* Wrel2  = (const float*)d_in[6];
    const float* brel2  = (const float*)d_in[7];
    const float* Wroot2 = (const float*)d_in[8];
    float* out = (float*)d_out;

    const int N = in_sizes[0] / NF;     // 100000
    const int E = in_sizes[2];          // 1000000

    // workspace layout (floats)
    float* ws   = (float*)d_ws;
    float* agg  = ws;                       // N*64 (layer1), reused as N*32 (layer2)
    float* cnt  = ws + (size_t)N * 64;      // N
    int*   flag = (int*)(ws + (size_t)N * 65);   // 4 floats reserved
    float* h    = ws + (size_t)N * 65 + 4;  // N*64
    float* hr   = h + (size_t)N * 64;       // N*32
    int*   src  = (int*)(hr + (size_t)N * 32);   // E
    int*   dst  = src + E;                       // E

    // zero agg1 + cnt + flag
    hipMemsetAsync(ws, 0, ((size_t)N * 65 + 4) * sizeof(float), stream);

    detect_i64<<<1, 256, 0, stream>>>((const unsigned*)ei_raw, flag);
    convert_idx<<<(E + 255) / 256, 256, 0, stream>>>(ei_raw, flag, src, dst, E);

    // layer 1
    scatter64<<<(E * 16 + 255) / 256, 256, 0, stream>>>(x, src, dst, ea, agg, cnt, E);
    node1<<<(N + 3) / 4, 256, 0, stream>>>(x, agg, cnt, Wrel1, brel1, Wroot1, Wrel2, h, hr, N);

    // layer 2 (agg region reused, 32-wide)
    hipMemsetAsync(agg, 0, (size_t)N * 32 * sizeof(float), stream);
    scatter32<<<(E * 8 + 255) / 256, 256, 0, stream>>>(hr, src, dst, ea, agg, E);
    node2<<<(N + 3) / 4, 256, 0, stream>>>(h, agg, cnt, Wroot2, brel2, out, N);
}

// Round 2
// 406.183 us; speedup vs baseline: 3.7023x; 3.7023x over previous
//
#include <hip/hip_runtime.h>
#include <hip/hip_bf16.h>

// GraphConv x2 via dst-sorted CSR gather (no float atomics):
//   h   = sigmoid(mean_agg(x*w) @ Wrel1^T + b1 + x @ Wroot1^T)
//   hr  = h @ Wrel2^T                      (linear commutes with aggregation)
//   out = mean_agg(hr*w) + b2 + h @ Wroot2^T

#define NF 64

// ---------------- dtype detection (int64 vs int32 edge_index) ---------------
__global__ void detect_i64(const unsigned* __restrict__ raw, int* __restrict__ flag, int E) {
    __shared__ unsigned red[256];
    unsigned v = 0;
    int lim = (E < 4096) ? E : 4096;
    for (int i = threadIdx.x; i < lim; i += 256) v |= raw[2 * i + 1];
    red[threadIdx.x] = v;
    __syncthreads();
    for (int s = 128; s > 0; s >>= 1) {
        if (threadIdx.x < s) red[threadIdx.x] |= red[threadIdx.x + s];
        __syncthreads();
    }
    if (threadIdx.x == 0) *flag = (red[0] == 0) ? 1 : 0;  // high dwords all zero => int64
}

// ---------------- histogram of dst ------------------------------------------
__global__ __launch_bounds__(256) void hist(const void* __restrict__ raw,
                                            const int* __restrict__ flag,
                                            int* __restrict__ deg, int E) {
    int e = blockIdx.x * blockDim.x + threadIdx.x;
    if (e >= E) return;
    int d = (*flag) ? (int)((const long long*)raw)[E + e] : ((const int*)raw)[E + e];
    atomicAdd(&deg[d], 1);
}

// ---------------- exclusive scan (3 kernels) ---------------------------------
__global__ __launch_bounds__(1024) void scan_k1(const int* __restrict__ deg,
                                                int* __restrict__ base,
                                                int* __restrict__ bsums, int N) {
    __shared__ int tmp[1024];
    int tid = threadIdx.x;
    int i = blockIdx.x * 1024 + tid;
    int v = (i < N) ? deg[i] : 0;
    tmp[tid] = v;
    __syncthreads();
    for (int off = 1; off < 1024; off <<= 1) {
        int t = (tid >= off) ? tmp[tid - off] : 0;
        __syncthreads();
        tmp[tid] += t;
        __syncthreads();
    }
    if (i < N) base[i] = tmp[tid] - v;           // exclusive within block
    if (tid == 1023) bsums[blockIdx.x] = tmp[tid];
}

__global__ __launch_bounds__(256) void scan_k2(int* __restrict__ bsums, int nb) {
    __shared__ int tmp[256];
    int tid = threadIdx.x;
    int v = (tid < nb) ? bsums[tid] : 0;
    tmp[tid] = v;
    __syncthreads();
    for (int off = 1; off < 256; off <<= 1) {
        int t = (tid >= off) ? tmp[tid - off] : 0;
        __syncthreads();
        tmp[tid] += t;
        __syncthreads();
    }
    if (tid < nb) bsums[tid] = tmp[tid] - v;     // exclusive
}

__global__ __launch_bounds__(1024) void scan_k3(int* __restrict__ base,
                                                const int* __restrict__ bsums,
                                                int* __restrict__ cursor, int N) {
    int i = blockIdx.x * 1024 + threadIdx.x;
    if (i >= N) return;
    int b = base[i] + bsums[blockIdx.x];
    base[i] = b;
    cursor[i] = b;
}

// ---------------- fill CSR slots ---------------------------------------------
__global__ __launch_bounds__(256) void fill_csr(const void* __restrict__ raw,
                                                const int* __restrict__ flag,
                                                const float* __restrict__ ea,
                                                int* __restrict__ cursor,
                                                int2* __restrict__ csr, int E) {
    int e = blockIdx.x * blockDim.x + threadIdx.x;
    if (e >= E) return;
    int s, d;
    if (*flag) {
        const long long* p = (const long long*)raw;
        s = (int)p[e]; d = (int)p[E + e];
    } else {
        const int* p = (const int*)raw;
        s = p[e]; d = p[E + e];
    }
    int slot = atomicAdd(&cursor[d], 1);
    csr[slot] = make_int2(s, __float_as_int(ea[e]));
}

// ---- layer 1 fused: gather + h = sigmoid((agg/deg)@Wrel1^T + b1 + x@Wroot1^T)
// ----                + hr = h @ Wrel2^T
__global__ __launch_bounds__(256) void layer1(
    const float* __restrict__ x, const int2* __restrict__ csr,
    const int* __restrict__ base, const int* __restrict__ deg,
    const float* __restrict__ Wrel1, const float* __restrict__ brel1,
    const float* __restrict__ Wroot1, const float* __restrict__ Wrel2,
    float* __restrict__ h, float* __restrict__ hr, int N)
{
    __shared__ float wrel[64 * 65];   // [k][f], pad 65
    __shared__ float wroot[64 * 65];
    __shared__ float wrel2[64 * 33];  // [f][j]
    __shared__ float xs[4][64], as_[4][64], hs[4][64];
    int t = threadIdx.x;
    for (int i = t; i < 4096; i += 256) {
        int f = i >> 6, k = i & 63;
        wrel[k * 65 + f] = Wrel1[i];
        wroot[k * 65 + f] = Wroot1[i];
    }
    for (int i = t; i < 2048; i += 256) {
        int j = i >> 6, f = i & 63;   // Wrel2 is [32][64] row-major
        wrel2[f * 33 + j] = Wrel2[i];
    }
    __syncthreads();

    int lane = t & 63, wv = t >> 6;
    int nwaves = gridDim.x * 4;
    for (int n0 = blockIdx.x * 4; n0 < N; n0 += nwaves) {   // uniform per block
        int n = n0 + wv;
        bool valid = n < N;
        int b = 0, dg = 0;
        if (valid) { b = base[n]; dg = deg[n]; }

        // gather: acc = sum_e w_e * x[src_e][lane]
        float acc = 0.f;
        int i = b, end = b + dg;
        for (; i + 4 <= end; i += 4) {
            int2 r0 = csr[i], r1 = csr[i + 1], r2 = csr[i + 2], r3 = csr[i + 3];
            acc = fmaf(__int_as_float(r0.y), x[(size_t)r0.x * 64 + lane], acc);
            acc = fmaf(__int_as_float(r1.y), x[(size_t)r1.x * 64 + lane], acc);
            acc = fmaf(__int_as_float(r2.y), x[(size_t)r2.x * 64 + lane], acc);
            acc = fmaf(__int_as_float(r3.y), x[(size_t)r3.x * 64 + lane], acc);
        }
        for (; i < end; ++i) {
            int2 r = csr[i];
            acc = fmaf(__int_as_float(r.y), x[(size_t)r.x * 64 + lane], acc);
        }
        float inv = 1.0f / fmaxf((float)dg, 1.0f);
        float xv = valid ? x[(size_t)n * 64 + lane] : 0.f;
        xs[wv][lane] = xv;
        as_[wv][lane] = acc * inv;
        __syncthreads();

        float accr = brel1[lane], acco = 0.f;
#pragma unroll
        for (int k = 0; k < 64; ++k) {
            accr = fmaf(as_[wv][k], wrel[k * 65 + lane], accr);
            acco = fmaf(xs[wv][k], wroot[k * 65 + lane], acco);
        }
        float hv = 1.0f / (1.0f + __expf(-(accr + acco)));
        if (valid) h[(size_t)n * 64 + lane] = hv;
        hs[wv][lane] = hv;
        __syncthreads();

        // hr[j] = sum_f h[f]*Wrel2[j][f]; split K across lane halves
        int j = lane & 31, half = lane >> 5;
        float acc2 = 0.f;
#pragma unroll
        for (int k2 = 0; k2 < 32; ++k2) {
            int f = half * 32 + k2;
            acc2 = fmaf(hs[wv][f], wrel2[f * 33 + j], acc2);
        }
        acc2 += __shfl_xor(acc2, 32);
        if (half == 0 && valid) hr[(size_t)n * 32 + j] = acc2;
        __syncthreads();
    }
}

// ---- layer 2 fused: gather(hr) + out = agg2/deg + b2 + h @ Wroot2^T ---------
__global__ __launch_bounds__(256) void layer2(
    const float* __restrict__ h, const float* __restrict__ hr,
    const int2* __restrict__ csr, const int* __restrict__ base,
    const int* __restrict__ deg,
    const float* __restrict__ Wroot2, const float* __restrict__ brel2,
    float* __restrict__ out, int N)
{
    __shared__ float wroot[64 * 33];
    __shared__ float hs[4][64];
    int t = threadIdx.x;
    for (int i = t; i < 2048; i += 256) {
        int j = i >> 6, f = i & 63;   // Wroot2 is [32][64] row-major
        wroot[f * 33 + j] = Wroot2[i];
    }
    __syncthreads();

    int lane = t & 63, wv = t >> 6;
    int j = lane & 31, half = lane >> 5;
    int nwaves = gridDim.x * 4;
    for (int n0 = blockIdx.x * 4; n0 < N; n0 += nwaves) {
        int n = n0 + wv;
        bool valid = n < N;
        int b = 0, dg = 0;
        if (valid) { b = base[n]; dg = deg[n]; }

        // gather 32-wide hr, 2 edges per iteration across lane halves
        float agg2 = 0.f;
        for (int i = b + half; i < b + dg; i += 2) {
            int2 r = csr[i];
            agg2 = fmaf(__int_as_float(r.y), hr[(size_t)r.x * 32 + j], agg2);
        }
        agg2 += __shfl_xor(agg2, 32);   // half 0 now has full sum

        float hv = valid ? h[(size_t)n * 64 + lane] : 0.f;
        hs[wv][lane] = hv;
        __syncthreads();

        float acc = 0.f;
#pragma unroll
        for (int k2 = 0; k2 < 32; ++k2) {
            int f = half * 32 + k2;
            acc = fmaf(hs[wv][f], wroot[f * 33 + j], acc);
        }
        acc += __shfl_xor(acc, 32);
        if (half == 0 && valid) {
            float inv = 1.0f / fmaxf((float)dg, 1.0f);
            out[(size_t)n * 32 + j] = acc + agg2 * inv + brel2[j];
        }
        __syncthreads();
    }
}

extern "C" void kernel_launch(void* const* d_in, const int* in_sizes, int n_in,
                              void* d_out, int out_size, void* d_ws, size_t ws_size,
                              hipStream_t stream) {
    const float* x      = (const float*)d_in[0];
    const void*  ei_raw = d_in[1];
    const float* ea     = (const float*)d_in[2];
    const float* Wrel1  = (const float*)d_in[3];
    const float* brel1  = (const float*)d_in[4];
    const float* Wroot1 = (const float*)d_in[5];
    const float* Wrel2  = (const float*)d_in[6];
    const float* brel2  = (const float*)d_in[7];
    const float* Wroot2 = (const float*)d_in[8];
    float* out = (float*)d_out;

    const int N = in_sizes[0] / NF;     // 100000
    const int E = in_sizes[2];          // 1000000

    // workspace layout
    int2*  csr    = (int2*)d_ws;                    // E
    int*   deg    = (int*)(csr + E);                // N
    int*   base   = deg + N;                        // N
    int*   cursor = base + N;                       // N
    int*   bsums  = cursor + N;                     // 256
    int*   flag   = bsums + 256;                    // 1 (+3 pad)
    float* h      = (float*)(flag + 4);             // N*64
    float* hr     = h + (size_t)N * 64;             // N*32

    const int nb1 = (N + 1023) / 1024;

    hipMemsetAsync(deg, 0, (size_t)N * sizeof(int), stream);
    detect_i64<<<1, 256, 0, stream>>>((const unsigned*)ei_raw, flag, E);
    hist<<<(E + 255) / 256, 256, 0, stream>>>(ei_raw, flag, deg, E);
    scan_k1<<<nb1, 1024, 0, stream>>>(deg, base, bsums, N);
    scan_k2<<<1, 256, 0, stream>>>(bsums, nb1);
    scan_k3<<<nb1, 1024, 0, stream>>>(base, bsums, cursor, N);
    fill_csr<<<(E + 255) / 256, 256, 0, stream>>>(ei_raw, flag, ea, cursor, csr, E);

    layer1<<<2048, 256, 0, stream>>>(x, csr, base, deg, Wrel1, brel1, Wroot1, Wrel2, h, hr, N);
    layer2<<<2048, 256, 0, stream>>>(h, hr, csr, base, deg, Wroot2, brel2, out, N);
}

// Round 3
// 351.527 us; speedup vs baseline: 4.2779x; 1.1555x over previous
//
#include <hip/hip_runtime.h>
#include <hip/hip_bf16.h>

// GraphConv x2 via dst-sorted CSR gather (no float atomics), split kernels:
//   gather1: aggm = mean_e w*x[src]            (high occupancy, no LDS)
//   nodeA:   h    = sigmoid(aggm@Wrel1^T + b1 + x@Wroot1^T)  (reg-resident W)
//   nodeB:   hr   = h@Wrel2^T ; hro = h@Wroot2^T + b2        (reg-resident W)
//   gather2: out  = mean_e w*hr[src] + hro     (epilogue fused)

#define NF 64

// ---------------- dtype detection (int64 vs int32 edge_index) ---------------
__global__ void detect_i64(const unsigned* __restrict__ raw, int* __restrict__ flag, int E) {
    __shared__ unsigned red[256];
    unsigned v = 0;
    int lim = (E < 4096) ? E : 4096;
    for (int i = threadIdx.x; i < lim; i += 256) v |= raw[2 * i + 1];
    red[threadIdx.x] = v;
    __syncthreads();
    for (int s = 128; s > 0; s >>= 1) {
        if (threadIdx.x < s) red[threadIdx.x] |= red[threadIdx.x + s];
        __syncthreads();
    }
    if (threadIdx.x == 0) *flag = (red[0] == 0) ? 1 : 0;  // high dwords zero => int64
}

// ---------------- histogram of dst ------------------------------------------
__global__ __launch_bounds__(256) void hist(const void* __restrict__ raw,
                                            const int* __restrict__ flag,
                                            int* __restrict__ deg, int E) {
    int e = blockIdx.x * blockDim.x + threadIdx.x;
    if (e >= E) return;
    int d = (*flag) ? (int)((const long long*)raw)[E + e] : ((const int*)raw)[E + e];
    atomicAdd(&deg[d], 1);
}

// ---------------- exclusive scan (3 kernels) ---------------------------------
__global__ __launch_bounds__(1024) void scan_k1(const int* __restrict__ deg,
                                                int* __restrict__ base,
                                                int* __restrict__ bsums, int N) {
    __shared__ int tmp[1024];
    int tid = threadIdx.x;
    int i = blockIdx.x * 1024 + tid;
    int v = (i < N) ? deg[i] : 0;
    tmp[tid] = v;
    __syncthreads();
    for (int off = 1; off < 1024; off <<= 1) {
        int t = (tid >= off) ? tmp[tid - off] : 0;
        __syncthreads();
        tmp[tid] += t;
        __syncthreads();
    }
    if (i < N) base[i] = tmp[tid] - v;
    if (tid == 1023) bsums[blockIdx.x] = tmp[tid];
}

__global__ __launch_bounds__(256) void scan_k2(int* __restrict__ bsums, int nb) {
    __shared__ int tmp[256];
    int tid = threadIdx.x;
    int v = (tid < nb) ? bsums[tid] : 0;
    tmp[tid] = v;
    __syncthreads();
    for (int off = 1; off < 256; off <<= 1) {
        int t = (tid >= off) ? tmp[tid - off] : 0;
        __syncthreads();
        tmp[tid] += t;
        __syncthreads();
    }
    if (tid < nb) bsums[tid] = tmp[tid] - v;
}

__global__ __launch_bounds__(1024) void scan_k3(int* __restrict__ base,
                                                const int* __restrict__ bsums,
                                                int* __restrict__ cursor, int N) {
    int i = blockIdx.x * 1024 + threadIdx.x;
    if (i >= N) return;
    int b = base[i] + bsums[blockIdx.x];
    base[i] = b;
    cursor[i] = b;
}

// ---------------- fill CSR slots ---------------------------------------------
__global__ __launch_bounds__(256) void fill_csr(const void* __restrict__ raw,
                                                const int* __restrict__ flag,
                                                const float* __restrict__ ea,
                                                int* __restrict__ cursor,
                                                int2* __restrict__ csr, int E) {
    int e = blockIdx.x * blockDim.x + threadIdx.x;
    if (e >= E) return;
    int s, d;
    if (*flag) {
        const long long* p = (const long long*)raw;
        s = (int)p[e]; d = (int)p[E + e];
    } else {
        const int* p = (const int*)raw;
        s = p[e]; d = p[E + e];
    }
    int slot = atomicAdd(&cursor[d], 1);
    csr[slot] = make_int2(s, __float_as_int(ea[e]));
}

// ---------------- gather1: aggm[n] = (sum_e w*x[src])/max(deg,1) -------------
__global__ __launch_bounds__(256) void gather1(
    const float* __restrict__ x, const int2* __restrict__ csr,
    const int* __restrict__ base, const int* __restrict__ deg,
    float* __restrict__ aggm, int N)
{
    int lane = threadIdx.x & 63;
    int wid = blockIdx.x * 4 + (threadIdx.x >> 6);
    int stride = gridDim.x * 4;
    for (int n = wid; n < N; n += stride) {
        int b = __builtin_amdgcn_readfirstlane(base[n]);
        int dg = __builtin_amdgcn_readfirstlane(deg[n]);
        float acc0 = 0.f, acc1 = 0.f;
        int i = b, e = b + dg;
        for (; i + 4 <= e; i += 4) {
            int2 r0 = csr[i], r1 = csr[i + 1], r2 = csr[i + 2], r3 = csr[i + 3];
            float v0 = x[(size_t)r0.x * 64 + lane];
            float v1 = x[(size_t)r1.x * 64 + lane];
            float v2 = x[(size_t)r2.x * 64 + lane];
            float v3 = x[(size_t)r3.x * 64 + lane];
            acc0 = fmaf(__int_as_float(r0.y), v0, acc0);
            acc1 = fmaf(__int_as_float(r1.y), v1, acc1);
            acc0 = fmaf(__int_as_float(r2.y), v2, acc0);
            acc1 = fmaf(__int_as_float(r3.y), v3, acc1);
        }
        for (; i < e; ++i) {
            int2 r = csr[i];
            acc0 = fmaf(__int_as_float(r.y), x[(size_t)r.x * 64 + lane], acc0);
        }
        float inv = 1.0f / fmaxf((float)dg, 1.0f);
        aggm[(size_t)n * 64 + lane] = (acc0 + acc1) * inv;
    }
}

// ---------------- nodeA: h = sigmoid(aggm@Wrel1^T + b1 + x@Wroot1^T) ---------
// lane = output feature f; weight rows live in registers; activation rows are
// wave-uniform (scalar) loads.
__global__ __launch_bounds__(256, 2) void nodeA(
    const float* __restrict__ x, const float* __restrict__ aggm,
    const float* __restrict__ Wrel1, const float* __restrict__ brel1,
    const float* __restrict__ Wroot1, float* __restrict__ h, int N)
{
    int lane = threadIdx.x & 63;
    float4 wr[16], wo[16];
#pragma unroll
    for (int c = 0; c < 16; ++c) {
        wr[c] = *(const float4*)(Wrel1 + (size_t)lane * 64 + 4 * c);
        wo[c] = *(const float4*)(Wroot1 + (size_t)lane * 64 + 4 * c);
    }
    float bias = brel1[lane];
    int wid = blockIdx.x * 4 + (threadIdx.x >> 6);
    int stride = gridDim.x * 4;
    for (int n0 = wid; n0 < N; n0 += stride) {
        int n = __builtin_amdgcn_readfirstlane(n0);
        const float* ar = aggm + (size_t)n * 64;
        const float* xr = x + (size_t)n * 64;
        float accr = bias, acco = 0.f;
#pragma unroll
        for (int c = 0; c < 16; ++c) {
            float4 a = *(const float4*)(ar + 4 * c);
            float4 xv = *(const float4*)(xr + 4 * c);
            accr = fmaf(a.x, wr[c].x, accr);
            accr = fmaf(a.y, wr[c].y, accr);
            accr = fmaf(a.z, wr[c].z, accr);
            accr = fmaf(a.w, wr[c].w, accr);
            acco = fmaf(xv.x, wo[c].x, acco);
            acco = fmaf(xv.y, wo[c].y, acco);
            acco = fmaf(xv.z, wo[c].z, acco);
            acco = fmaf(xv.w, wo[c].w, acco);
        }
        float z = accr + acco;
        h[(size_t)n * 64 + lane] = 1.0f / (1.0f + __expf(-z));
    }
}

// ---------------- nodeB: hr = h@Wrel2^T ; hro = h@Wroot2^T + b2 --------------
// lanes 0..31 -> hr row j=lane; lanes 32..63 -> hro row j=lane-32.
__global__ __launch_bounds__(256) void nodeB(
    const float* __restrict__ h, const float* __restrict__ Wrel2,
    const float* __restrict__ brel2, const float* __restrict__ Wroot2,
    float* __restrict__ hr, float* __restrict__ hro, int N)
{
    int lane = threadIdx.x & 63;
    int j = lane & 31;
    bool isRel = lane < 32;
    const float* Wsrc = isRel ? Wrel2 : Wroot2;
    float4 w[16];
#pragma unroll
    for (int c = 0; c < 16; ++c) w[c] = *(const float4*)(Wsrc + (size_t)j * 64 + 4 * c);
    float bias = isRel ? 0.f : brel2[j];
    float* dstbuf = isRel ? hr : hro;

    int wid = blockIdx.x * 4 + (threadIdx.x >> 6);
    int stride = gridDim.x * 4;
    for (int n0 = wid; n0 < N; n0 += stride) {
        int n = __builtin_amdgcn_readfirstlane(n0);
        const float* hrow = h + (size_t)n * 64;
        float acc = bias;
#pragma unroll
        for (int c = 0; c < 16; ++c) {
            float4 hv = *(const float4*)(hrow + 4 * c);
            acc = fmaf(hv.x, w[c].x, acc);
            acc = fmaf(hv.y, w[c].y, acc);
            acc = fmaf(hv.z, w[c].z, acc);
            acc = fmaf(hv.w, w[c].w, acc);
        }
        dstbuf[(size_t)n * 32 + j] = acc;
    }
}

// ---------------- gather2 + epilogue: out = agg2/deg + hro -------------------
__global__ __launch_bounds__(256) void gather2(
    const float* __restrict__ hr, const float* __restrict__ hro,
    const int2* __restrict__ csr, const int* __restrict__ base,
    const int* __restrict__ deg, float* __restrict__ out, int N)
{
    int lane = threadIdx.x & 63;
    int j = lane & 31, half = lane >> 5;
    int wid = blockIdx.x * 4 + (threadIdx.x >> 6);
    int stride = gridDim.x * 4;
    for (int n = wid; n < N; n += stride) {
        int b = __builtin_amdgcn_readfirstlane(base[n]);
        int dg = __builtin_amdgcn_readfirstlane(deg[n]);
        float a0 = 0.f, a1 = 0.f;
        int i = b + half, e = b + dg;
        for (; i + 4 <= e; i += 4) {   // this half handles i and i+2
            int2 r0 = csr[i], r1 = csr[i + 2];
            a0 = fmaf(__int_as_float(r0.y), hr[(size_t)r0.x * 32 + j], a0);
            a1 = fmaf(__int_as_float(r1.y), hr[(size_t)r1.x * 32 + j], a1);
        }
        for (; i < e; i += 2) {
            int2 r = csr[i];
            a0 = fmaf(__int_as_float(r.y), hr[(size_t)r.x * 32 + j], a0);
        }
        float acc = a0 + a1;
        acc += __shfl_xor(acc, 32);
        if (half == 0) {
            float inv = 1.0f / fmaxf((float)dg, 1.0f);
            out[(size_t)n * 32 + j] = acc * inv + hro[(size_t)n * 32 + j];
        }
    }
}

extern "C" void kernel_launch(void* const* d_in, const int* in_sizes, int n_in,
                              void* d_out, int out_size, void* d_ws, size_t ws_size,
                              hipStream_t stream) {
    const float* x      = (const float*)d_in[0];
    const void*  ei_raw = d_in[1];
    const float* ea     = (const float*)d_in[2];
    const float* Wrel1  = (const float*)d_in[3];
    const float* brel1  = (const float*)d_in[4];
    const float* Wroot1 = (const float*)d_in[5];
    const float* Wrel2  = (const float*)d_in[6];
    const float* brel2  = (const float*)d_in[7];
    const float* Wroot2 = (const float*)d_in[8];
    float* out = (float*)d_out;

    const int N = in_sizes[0] / NF;     // 100000
    const int E = in_sizes[2];          // 1000000

    // workspace layout
    int2*  csr    = (int2*)d_ws;                    // E
    int*   deg    = (int*)(csr + E);                // N
    int*   base   = deg + N;                        // N
    int*   cursor = base + N;                       // N
    int*   bsums  = cursor + N;                     // 256
    int*   flag   = bsums + 256;                    // 1 (+3 pad)
    float* aggm   = (float*)(flag + 4);             // N*64 ; reused as hr|hro
    float* h      = aggm + (size_t)N * 64;          // N*64
    float* hr     = aggm;                           // N*32 (aggm dead after nodeA)
    float* hro    = aggm + (size_t)N * 32;          // N*32

    const int nb1 = (N + 1023) / 1024;

    hipMemsetAsync(deg, 0, (size_t)N * sizeof(int), stream);
    detect_i64<<<1, 256, 0, stream>>>((const unsigned*)ei_raw, flag, E);
    hist<<<(E + 255) / 256, 256, 0, stream>>>(ei_raw, flag, deg, E);
    scan_k1<<<nb1, 1024, 0, stream>>>(deg, base, bsums, N);
    scan_k2<<<1, 256, 0, stream>>>(bsums, nb1);
    scan_k3<<<nb1, 1024, 0, stream>>>(base, bsums, cursor, N);
    fill_csr<<<(E + 255) / 256, 256, 0, stream>>>(ei_raw, flag, ea, cursor, csr, E);

    gather1<<<2048, 256, 0, stream>>>(x, csr, base, deg, aggm, N);
    nodeA<<<512, 256, 0, stream>>>(x, aggm, Wrel1, brel1, Wroot1, h, N);
    nodeB<<<512, 256, 0, stream>>>(h, Wrel2, brel2, Wroot2, hr, hro, N);
    gather2<<<2048, 256, 0, stream>>>(hr, hro, csr, base, deg, out, N);
}

// Round 4
// 331.621 us; speedup vs baseline: 4.5347x; 1.0600x over previous
//
#include <hip/hip_runtime.h>
#include <hip/hip_bf16.h>

// GraphConv x2 via dst-sorted CSR gather (no float atomics), split kernels:
//   gather1: aggm = mean_e w*x[src]            (high occupancy, no LDS)
//   nodeA:   h    = sigmoid(aggm@Wrel1^T + b1 + x@Wroot1^T)
//   nodeB:   hr   = h@Wrel2^T ; hro = h@Wroot2^T + b2
//   gather2: out  = mean_e w*hr[src] + hro     (epilogue fused)

#define NF 64

// ---------------- dtype detection (int64 vs int32 edge_index) ---------------
__global__ void detect_i64(const unsigned* __restrict__ raw, int* __restrict__ flag, int E) {
    __shared__ unsigned red[256];
    unsigned v = 0;
    int lim = (E < 4096) ? E : 4096;
    for (int i = threadIdx.x; i < lim; i += 256) v |= raw[2 * i + 1];
    red[threadIdx.x] = v;
    __syncthreads();
    for (int s = 128; s > 0; s >>= 1) {
        if (threadIdx.x < s) red[threadIdx.x] |= red[threadIdx.x + s];
        __syncthreads();
    }
    if (threadIdx.x == 0) *flag = (red[0] == 0) ? 1 : 0;  // high dwords zero => int64
}

// ---------------- histogram of dst ------------------------------------------
__global__ __launch_bounds__(256) void hist(const void* __restrict__ raw,
                                            const int* __restrict__ flag,
                                            int* __restrict__ deg, int E) {
    int e = blockIdx.x * blockDim.x + threadIdx.x;
    if (e >= E) return;
    int d = (*flag) ? (int)((const long long*)raw)[E + e] : ((const int*)raw)[E + e];
    atomicAdd(&deg[d], 1);
}

// ---------------- exclusive scan (3 kernels) ---------------------------------
__global__ __launch_bounds__(1024) void scan_k1(const int* __restrict__ deg,
                                                int* __restrict__ base,
                                                int* __restrict__ bsums, int N) {
    __shared__ int tmp[1024];
    int tid = threadIdx.x;
    int i = blockIdx.x * 1024 + tid;
    int v = (i < N) ? deg[i] : 0;
    tmp[tid] = v;
    __syncthreads();
    for (int off = 1; off < 1024; off <<= 1) {
        int t = (tid >= off) ? tmp[tid - off] : 0;
        __syncthreads();
        tmp[tid] += t;
        __syncthreads();
    }
    if (i < N) base[i] = tmp[tid] - v;
    if (tid == 1023) bsums[blockIdx.x] = tmp[tid];
}

__global__ __launch_bounds__(256) void scan_k2(int* __restrict__ bsums, int nb) {
    __shared__ int tmp[256];
    int tid = threadIdx.x;
    int v = (tid < nb) ? bsums[tid] : 0;
    tmp[tid] = v;
    __syncthreads();
    for (int off = 1; off < 256; off <<= 1) {
        int t = (tid >= off) ? tmp[tid - off] : 0;
        __syncthreads();
        tmp[tid] += t;
        __syncthreads();
    }
    if (tid < nb) bsums[tid] = tmp[tid] - v;
}

__global__ __launch_bounds__(1024) void scan_k3(int* __restrict__ base,
                                                const int* __restrict__ bsums,
                                                int* __restrict__ cursor, int N) {
    int i = blockIdx.x * 1024 + threadIdx.x;
    if (i >= N) return;
    int b = base[i] + bsums[blockIdx.x];
    base[i] = b;
    cursor[i] = b;
}

// ---------------- fill CSR slots ---------------------------------------------
__global__ __launch_bounds__(256) void fill_csr(const void* __restrict__ raw,
                                                const int* __restrict__ flag,
                                                const float* __restrict__ ea,
                                                int* __restrict__ cursor,
                                                int2* __restrict__ csr, int E) {
    int e = blockIdx.x * blockDim.x + threadIdx.x;
    if (e >= E) return;
    int s, d;
    if (*flag) {
        const long long* p = (const long long*)raw;
        s = (int)p[e]; d = (int)p[E + e];
    } else {
        const int* p = (const int*)raw;
        s = p[e]; d = p[E + e];
    }
    int slot = atomicAdd(&cursor[d], 1);
    csr[slot] = make_int2(s, __float_as_int(ea[e]));
}

// ---------------- gather1: aggm[n] = (sum_e w*x[src])/max(deg,1) -------------
__global__ __launch_bounds__(256) void gather1(
    const float* __restrict__ x, const int2* __restrict__ csr,
    const int* __restrict__ base, const int* __restrict__ deg,
    float* __restrict__ aggm, int N)
{
    int lane = threadIdx.x & 63;
    int wid = blockIdx.x * 4 + (threadIdx.x >> 6);
    int stride = gridDim.x * 4;
    for (int n = wid; n < N; n += stride) {
        int b = __builtin_amdgcn_readfirstlane(base[n]);
        int dg = __builtin_amdgcn_readfirstlane(deg[n]);
        float acc0 = 0.f, acc1 = 0.f;
        int i = b, e = b + dg;
        for (; i + 4 <= e; i += 4) {
            int2 r0 = csr[i], r1 = csr[i + 1], r2 = csr[i + 2], r3 = csr[i + 3];
            float v0 = x[(size_t)r0.x * 64 + lane];
            float v1 = x[(size_t)r1.x * 64 + lane];
            float v2 = x[(size_t)r2.x * 64 + lane];
            float v3 = x[(size_t)r3.x * 64 + lane];
            acc0 = fmaf(__int_as_float(r0.y), v0, acc0);
            acc1 = fmaf(__int_as_float(r1.y), v1, acc1);
            acc0 = fmaf(__int_as_float(r2.y), v2, acc0);
            acc1 = fmaf(__int_as_float(r3.y), v3, acc1);
        }
        for (; i < e; ++i) {
            int2 r = csr[i];
            acc0 = fmaf(__int_as_float(r.y), x[(size_t)r.x * 64 + lane], acc0);
        }
        float inv = 1.0f / fmaxf((float)dg, 1.0f);
        aggm[(size_t)n * 64 + lane] = (acc0 + acc1) * inv;
    }
}

// ---------------- nodeA: h = sigmoid(aggm@Wrel1^T + b1 + x@Wroot1^T) ---------
// lane = output feature f. Two nodes per iteration for ILP; weight loads are
// L1-resident and amortized over both nodes.
__global__ __launch_bounds__(256) void nodeA(
    const float* __restrict__ x, const float* __restrict__ aggm,
    const float* __restrict__ Wrel1, const float* __restrict__ brel1,
    const float* __restrict__ Wroot1, float* __restrict__ h, int N)
{
    int lane = threadIdx.x & 63;
    const float* wrp = Wrel1 + (size_t)lane * 64;
    const float* wop = Wroot1 + (size_t)lane * 64;
    float bias = brel1[lane];
    int wid = blockIdx.x * 4 + (threadIdx.x >> 6);
    int stride = gridDim.x * 4;
    for (int n0 = wid * 2; n0 < N; n0 += stride * 2) {
        int nA = __builtin_amdgcn_readfirstlane(n0);
        int nBv = n0 + 1 < N ? n0 + 1 : n0;
        int nB = __builtin_amdgcn_readfirstlane(nBv);
        const float* ar0 = aggm + (size_t)nA * 64;
        const float* xr0 = x + (size_t)nA * 64;
        const float* ar1 = aggm + (size_t)nB * 64;
        const float* xr1 = x + (size_t)nB * 64;
        float accr0 = bias, acco0 = 0.f, accr1 = bias, acco1 = 0.f;
#pragma unroll
        for (int c = 0; c < 16; ++c) {
            float4 w_r = *(const float4*)(wrp + 4 * c);
            float4 w_o = *(const float4*)(wop + 4 * c);
            float4 a0 = *(const float4*)(ar0 + 4 * c);
            float4 x0 = *(const float4*)(xr0 + 4 * c);
            float4 a1 = *(const float4*)(ar1 + 4 * c);
            float4 x1 = *(const float4*)(xr1 + 4 * c);
            accr0 = fmaf(a0.x, w_r.x, accr0); accr1 = fmaf(a1.x, w_r.x, accr1);
            accr0 = fmaf(a0.y, w_r.y, accr0); accr1 = fmaf(a1.y, w_r.y, accr1);
            accr0 = fmaf(a0.z, w_r.z, accr0); accr1 = fmaf(a1.z, w_r.z, accr1);
            accr0 = fmaf(a0.w, w_r.w, accr0); accr1 = fmaf(a1.w, w_r.w, accr1);
            acco0 = fmaf(x0.x, w_o.x, acco0); acco1 = fmaf(x1.x, w_o.x, acco1);
            acco0 = fmaf(x0.y, w_o.y, acco0); acco1 = fmaf(x1.y, w_o.y, acco1);
            acco0 = fmaf(x0.z, w_o.z, acco0); acco1 = fmaf(x1.z, w_o.z, acco1);
            acco0 = fmaf(x0.w, w_o.w, acco0); acco1 = fmaf(x1.w, w_o.w, acco1);
        }
        float h0 = 1.0f / (1.0f + __expf(-(accr0 + acco0)));
        float h1 = 1.0f / (1.0f + __expf(-(accr1 + acco1)));
        h[(size_t)nA * 64 + lane] = h0;
        if (n0 + 1 < N) h[(size_t)nB * 64 + lane] = h1;
    }
}

// ---------------- nodeB: hr = h@Wrel2^T ; hro = h@Wroot2^T + b2 --------------
// lanes 0..31 -> hr row j=lane; lanes 32..63 -> hro row j=lane-32.
__global__ __launch_bounds__(256) void nodeB(
    const float* __restrict__ h, const float* __restrict__ Wrel2,
    const float* __restrict__ brel2, const float* __restrict__ Wroot2,
    float* __restrict__ hr, float* __restrict__ hro, int N)
{
    int lane = threadIdx.x & 63;
    int j = lane & 31;
    bool isRel = lane < 32;
    const float* wp = (isRel ? Wrel2 : Wroot2) + (size_t)j * 64;
    float bias = isRel ? 0.f : brel2[j];
    float* dstbuf = isRel ? hr : hro;

    int wid = blockIdx.x * 4 + (threadIdx.x >> 6);
    int stride = gridDim.x * 4;
    for (int n0 = wid * 2; n0 < N; n0 += stride * 2) {
        int nA = __builtin_amdgcn_readfirstlane(n0);
        int nBv = n0 + 1 < N ? n0 + 1 : n0;
        int nB = __builtin_amdgcn_readfirstlane(nBv);
        const float* h0 = h + (size_t)nA * 64;
        const float* h1 = h + (size_t)nB * 64;
        float acc0 = bias, acc1 = bias;
#pragma unroll
        for (int c = 0; c < 16; ++c) {
            float4 w = *(const float4*)(wp + 4 * c);
            float4 v0 = *(const float4*)(h0 + 4 * c);
            float4 v1 = *(const float4*)(h1 + 4 * c);
            acc0 = fmaf(v0.x, w.x, acc0); acc1 = fmaf(v1.x, w.x, acc1);
            acc0 = fmaf(v0.y, w.y, acc0); acc1 = fmaf(v1.y, w.y, acc1);
            acc0 = fmaf(v0.z, w.z, acc0); acc1 = fmaf(v1.z, w.z, acc1);
            acc0 = fmaf(v0.w, w.w, acc0); acc1 = fmaf(v1.w, w.w, acc1);
        }
        dstbuf[(size_t)nA * 32 + j] = acc0;
        if (n0 + 1 < N) dstbuf[(size_t)nB * 32 + j] = acc1;
    }
}

// ---------------- gather2 + epilogue: out = agg2/deg + hro -------------------
__global__ __launch_bounds__(256) void gather2(
    const float* __restrict__ hr, const float* __restrict__ hro,
    const int2* __restrict__ csr, const int* __restrict__ base,
    const int* __restrict__ deg, float* __restrict__ out, int N)
{
    int lane = threadIdx.x & 63;
    int j = lane & 31, half = lane >> 5;
    int wid = blockIdx.x * 4 + (threadIdx.x >> 6);
    int stride = gridDim.x * 4;
    for (int n = wid; n < N; n += stride) {
        int b = __builtin_amdgcn_readfirstlane(base[n]);
        int dg = __builtin_amdgcn_readfirstlane(deg[n]);
        float a0 = 0.f, a1 = 0.f;
        int i = b + half, e = b + dg;
        for (; i + 4 <= e; i += 4) {   // this half handles i and i+2
            int2 r0 = csr[i], r1 = csr[i + 2];
            a0 = fmaf(__int_as_float(r0.y), hr[(size_t)r0.x * 32 + j], a0);
            a1 = fmaf(__int_as_float(r1.y), hr[(size_t)r1.x * 32 + j], a1);
        }
        for (; i < e; i += 2) {
            int2 r = csr[i];
            a0 = fmaf(__int_as_float(r.y), hr[(size_t)r.x * 32 + j], a0);
        }
        float acc = a0 + a1;
        acc += __shfl_xor(acc, 32);
        if (half == 0) {
            float inv = 1.0f / fmaxf((float)dg, 1.0f);
            out[(size_t)n * 32 + j] = acc * inv + hro[(size_t)n * 32 + j];
        }
    }
}

extern "C" void kernel_launch(void* const* d_in, const int* in_sizes, int n_in,
                              void* d_out, int out_size, void* d_ws, size_t ws_size,
                              hipStream_t stream) {
    const float* x      = (const float*)d_in[0];
    const void*  ei_raw = d_in[1];
    const float* ea     = (const float*)d_in[2];
    const float* Wrel1  = (const float*)d_in[3];
    const float* brel1  = (const float*)d_in[4];
    const float* Wroot1 = (const float*)d_in[5];
    const float* Wrel2  = (const float*)d_in[6];
    const float* brel2  = (const float*)d_in[7];
    const float* Wroot2 = (const float*)d_in[8];
    float* out = (float*)d_out;

    const int N = in_sizes[0] / NF;     // 100000
    const int E = in_sizes[2];          // 1000000

    // workspace layout
    int2*  csr    = (int2*)d_ws;                    // E
    int*   deg    = (int*)(csr + E);                // N
    int*   base   = deg + N;                        // N
    int*   cursor = base + N;                       // N
    int*   bsums  = cursor + N;                     // 256
    int*   flag   = bsums + 256;                    // 1 (+3 pad)
    float* aggm   = (float*)(flag + 4);             // N*64 ; reused as hr|hro
    float* h      = aggm + (size_t)N * 64;          // N*64
    float* hr     = aggm;                           // N*32 (aggm dead after nodeA)
    float* hro    = aggm + (size_t)N * 32;          // N*32

    const int nb1 = (N + 1023) / 1024;

    hipMemsetAsync(deg, 0, (size_t)N * sizeof(int), stream);
    detect_i64<<<1, 256, 0, stream>>>((const unsigned*)ei_raw, flag, E);
    hist<<<(E + 255) / 256, 256, 0, stream>>>(ei_raw, flag, deg, E);
    scan_k1<<<nb1, 1024, 0, stream>>>(deg, base, bsums, N);
    scan_k2<<<1, 256, 0, stream>>>(bsums, nb1);
    scan_k3<<<nb1, 1024, 0, stream>>>(base, bsums, cursor, N);
    fill_csr<<<(E + 255) / 256, 256, 0, stream>>>(ei_raw, flag, ea, cursor, csr, E);

    gather1<<<2048, 256, 0, stream>>>(x, csr, base, deg, aggm, N);
    nodeA<<<2048, 256, 0, stream>>>(x, aggm, Wrel1, brel1, Wroot1, h, N);
    nodeB<<<2048, 256, 0, stream>>>(h, Wrel2, brel2, Wroot2, hr, hro, N);
    gather2<<<2048, 256, 0, stream>>>(hr, hro, csr, base, deg, out, N);
}